// Round 10
// baseline (553.121 us; speedup 1.0000x reference)
//
#include <hip/hip_runtime.h>

#define N_NODES 100000
#define N_EDGES 1600000
#define D_FEAT  64
#define K_STEPS 8
#define NB_SCAN ((N_NODES + 255) / 256)   // 391 scan blocks

typedef unsigned long long u64;
typedef float f4 __attribute__((ext_vector_type(4)));

__global__ void k_zero(int* __restrict__ p, int n) {
    int i = blockIdx.x * blockDim.x + threadIdx.x;
    if (i < n) p[i] = 0;
}

// Histogram + per-edge rank. 8 edges/thread: 8 independent returning atomics
// in flight (diagnostic: if dur unchanged vs 4/thread, hist is at the
// returning-atomic throughput ceiling, not latency-bound).
__global__ void k_hist(const int* __restrict__ dst, int* __restrict__ counts,
                       int* __restrict__ rank, int n) {
    int base = (blockIdx.x * blockDim.x + threadIdx.x) * 8;
    if (base >= n) return;
    int4 dA = *reinterpret_cast<const int4*>(&dst[base]);
    int4 dB = *reinterpret_cast<const int4*>(&dst[base + 4]);
    int r0 = atomicAdd(&counts[dA.x], 1);
    int r1 = atomicAdd(&counts[dA.y], 1);
    int r2 = atomicAdd(&counts[dA.z], 1);
    int r3 = atomicAdd(&counts[dA.w], 1);
    int r4 = atomicAdd(&counts[dB.x], 1);
    int r5 = atomicAdd(&counts[dB.y], 1);
    int r6 = atomicAdd(&counts[dB.z], 1);
    int r7 = atomicAdd(&counts[dB.w], 1);
    *reinterpret_cast<int4*>(&rank[base])     = make_int4(r0, r1, r2, r3);
    *reinterpret_cast<int4*>(&rank[base + 4]) = make_int4(r4, r5, r6, r7);
}

// Phase 1: per-block sum of 256 counts
__global__ void k_bsum(const int* __restrict__ counts, int* __restrict__ blockSums, int n) {
    __shared__ int ws[4];
    int t = threadIdx.x;
    int i = blockIdx.x * 256 + t;
    int c = (i < n) ? counts[i] : 0;
    for (int off = 32; off; off >>= 1) c += __shfl_down(c, off);
    if ((t & 63) == 0) ws[t >> 6] = c;
    __syncthreads();
    if (t == 0) blockSums[blockIdx.x] = ws[0] + ws[1] + ws[2] + ws[3];
}

// Phase 2: single block scans the 391 block sums -> exclusive blockPrefix
__global__ void k_sscan(const int* __restrict__ blockSums, int* __restrict__ blockPrefix,
                        int* __restrict__ offsets, int nb, int n) {
    __shared__ int sh[512];
    int t = threadIdx.x;
    int v = (t < nb) ? blockSums[t] : 0;
    sh[t] = v;
    __syncthreads();
    for (int off = 1; off < 512; off <<= 1) {
        int u = (t >= off) ? sh[t - off] : 0;
        __syncthreads();
        sh[t] += u;
        __syncthreads();
    }
    if (t < nb) blockPrefix[t] = sh[t] - v;   // exclusive
    if (t == 511) offsets[n] = sh[511];        // total == N_EDGES
}

// Phase 3: per-block exclusive scan of counts + block prefix -> offsets
__global__ void k_bscan(const int* __restrict__ counts, const int* __restrict__ blockPrefix,
                        int* __restrict__ offsets, int n) {
    __shared__ int sh[256];
    int t = threadIdx.x;
    int i = blockIdx.x * 256 + t;
    int c = (i < n) ? counts[i] : 0;
    sh[t] = c;
    __syncthreads();
    for (int off = 1; off < 256; off <<= 1) {
        int u = (t >= off) ? sh[t - off] : 0;
        __syncthreads();
        sh[t] += u;
        __syncthreads();
    }
    int excl = sh[t] - c + blockPrefix[blockIdx.x];
    if (i < n) offsets[i] = excl;
}

// Atomic-free scatter, 8 edges/thread: 8 independent random offset reads and
// 8 independent 8B packed stores in flight. Cached stores keep csr LLC-hot.
__global__ void k_scatter(const int* __restrict__ src, const int* __restrict__ dst,
                          const float* __restrict__ w, const int* __restrict__ offsets,
                          const int* __restrict__ rank, u64* __restrict__ csr, int n) {
    int base = (blockIdx.x * blockDim.x + threadIdx.x) * 8;
    if (base >= n) return;
    int4   sA = *reinterpret_cast<const int4*>(&src[base]);
    int4   sB = *reinterpret_cast<const int4*>(&src[base + 4]);
    int4   dA = *reinterpret_cast<const int4*>(&dst[base]);
    int4   dB = *reinterpret_cast<const int4*>(&dst[base + 4]);
    float4 vA = *reinterpret_cast<const float4*>(&w[base]);
    float4 vB = *reinterpret_cast<const float4*>(&w[base + 4]);
    int4   rA = *reinterpret_cast<const int4*>(&rank[base]);
    int4   rB = *reinterpret_cast<const int4*>(&rank[base + 4]);
    int p0 = offsets[dA.x] + rA.x;
    int p1 = offsets[dA.y] + rA.y;
    int p2 = offsets[dA.z] + rA.z;
    int p3 = offsets[dA.w] + rA.w;
    int p4 = offsets[dB.x] + rB.x;
    int p5 = offsets[dB.y] + rB.y;
    int p6 = offsets[dB.z] + rB.z;
    int p7 = offsets[dB.w] + rB.w;
    csr[p0] = ((u64)__float_as_uint(vA.x) << 32) | (unsigned)sA.x;
    csr[p1] = ((u64)__float_as_uint(vA.y) << 32) | (unsigned)sA.y;
    csr[p2] = ((u64)__float_as_uint(vA.z) << 32) | (unsigned)sA.z;
    csr[p3] = ((u64)__float_as_uint(vA.w) << 32) | (unsigned)sA.w;
    csr[p4] = ((u64)__float_as_uint(vB.x) << 32) | (unsigned)sB.x;
    csr[p5] = ((u64)__float_as_uint(vB.y) << 32) | (unsigned)sB.y;
    csr[p6] = ((u64)__float_as_uint(vB.z) << 32) | (unsigned)sB.z;
    csr[p7] = ((u64)__float_as_uint(vB.w) << 32) | (unsigned)sB.w;
}

// One wave per node. lane = (edge_slot eg=lane>>3 [8 slots], fl=lane&7).
// 2-way unrolled: 16 edges in flight per iteration. OOB slot predicated to
// (row 0, w=0). All accesses cached: h + csr stay L2/LLC-resident.
__global__ __launch_bounds__(256)
void k_prop(const float* __restrict__ hin, float* __restrict__ hout,
            const int* __restrict__ offsets, const u64* __restrict__ csr, int n) {
    int wave = (blockIdx.x * blockDim.x + threadIdx.x) >> 6;
    int lane = threadIdx.x & 63;
    if (wave >= n) return;
    int b = offsets[wave];
    int e = offsets[wave + 1];
    int eg = lane >> 3;        // edge slot 0..7
    int fl = lane & 7;         // feature group (8 floats)
    f4 a0 = {0.f, 0.f, 0.f, 0.f};
    f4 a1 = {0.f, 0.f, 0.f, 0.f};
    f4 c0 = {0.f, 0.f, 0.f, 0.f};
    f4 c1 = {0.f, 0.f, 0.f, 0.f};
    for (int i = b + eg; i < e; i += 16) {
        int  iB  = i + 8;
        bool okB = iB < e;
        u64 pA = csr[i];
        u64 pB = okB ? csr[iB] : 0;
        int   sA = (int)(pA & 0xffffffffu);
        float wA = __uint_as_float((unsigned)(pA >> 32));
        int   sB = okB ? (int)(pB & 0xffffffffu) : 0;
        float wB = okB ? __uint_as_float((unsigned)(pB >> 32)) : 0.f;
        const f4* rA = reinterpret_cast<const f4*>(&hin[((size_t)sA << 6) + (fl << 3)]);
        const f4* rB = reinterpret_cast<const f4*>(&hin[((size_t)sB << 6) + (fl << 3)]);
        f4 vA0 = rA[0], vA1 = rA[1];
        f4 vB0 = rB[0], vB1 = rB[1];
        a0.x = fmaf(wA, vA0.x, a0.x); a0.y = fmaf(wA, vA0.y, a0.y);
        a0.z = fmaf(wA, vA0.z, a0.z); a0.w = fmaf(wA, vA0.w, a0.w);
        a1.x = fmaf(wA, vA1.x, a1.x); a1.y = fmaf(wA, vA1.y, a1.y);
        a1.z = fmaf(wA, vA1.z, a1.z); a1.w = fmaf(wA, vA1.w, a1.w);
        c0.x = fmaf(wB, vB0.x, c0.x); c0.y = fmaf(wB, vB0.y, c0.y);
        c0.z = fmaf(wB, vB0.z, c0.z); c0.w = fmaf(wB, vB0.w, c0.w);
        c1.x = fmaf(wB, vB1.x, c1.x); c1.y = fmaf(wB, vB1.y, c1.y);
        c1.z = fmaf(wB, vB1.z, c1.z); c1.w = fmaf(wB, vB1.w, c1.w);
    }
    a0.x += c0.x; a0.y += c0.y; a0.z += c0.z; a0.w += c0.w;
    a1.x += c1.x; a1.y += c1.y; a1.z += c1.z; a1.w += c1.w;
    #pragma unroll
    for (int off = 8; off < 64; off <<= 1) {
        a0.x += __shfl_xor(a0.x, off);
        a0.y += __shfl_xor(a0.y, off);
        a0.z += __shfl_xor(a0.z, off);
        a0.w += __shfl_xor(a0.w, off);
        a1.x += __shfl_xor(a1.x, off);
        a1.y += __shfl_xor(a1.y, off);
        a1.z += __shfl_xor(a1.z, off);
        a1.w += __shfl_xor(a1.w, off);
    }
    if (eg == 0) {
        f4* o = reinterpret_cast<f4*>(&hout[((size_t)wave << 6) + (fl << 3)]);
        o[0] = a0;
        o[1] = a1;
    }
}

extern "C" void kernel_launch(void* const* d_in, const int* in_sizes, int n_in,
                              void* d_out, int out_size, void* d_ws, size_t ws_size,
                              hipStream_t stream) {
    const float* x   = (const float*)d_in[0];
    const float* ew  = (const float*)d_in[1];
    const int*   src = (const int*)d_in[2];
    const int*   dst = (const int*)d_in[3];
    float* out = (float*)d_out;

    // Workspace (~39.7 MB). rank aliases hA: rank is consumed by k_scatter,
    // which completes before the first k_prop writes hA. Prop chain
    // ping-pongs hA <-> d_out; k=7 (odd) lands in d_out.
    float* hA         = (float*)d_ws;                           // N*D floats
    int*   rank       = (int*)d_ws;                             // E ints (aliases hA)
    u64*   csr        = (u64*)(hA + (size_t)N_NODES * D_FEAT);  // E x 8B packed (src,w)
    int*   offsets    = (int*)(csr + N_EDGES);                  // N+1 ints
    int*   counts     = offsets + (N_NODES + 1);                // N ints
    int*   blockSums  = counts + N_NODES;                       // NB_SCAN ints
    int*   blockPref  = blockSums + NB_SCAN;                    // NB_SCAN ints

    k_zero<<<(N_NODES + 255) / 256, 256, 0, stream>>>(counts, N_NODES);
    k_hist<<<(N_EDGES / 8 + 255) / 256, 256, 0, stream>>>(dst, counts, rank, N_EDGES);
    k_bsum<<<NB_SCAN, 256, 0, stream>>>(counts, blockSums, N_NODES);
    k_sscan<<<1, 512, 0, stream>>>(blockSums, blockPref, offsets, NB_SCAN, N_NODES);
    k_bscan<<<NB_SCAN, 256, 0, stream>>>(counts, blockPref, offsets, N_NODES);
    k_scatter<<<(N_EDGES / 8 + 255) / 256, 256, 0, stream>>>(src, dst, ew, offsets, rank,
                                                             csr, N_EDGES);

    const int prop_grid = (N_NODES * 64 + 255) / 256;
    const float* in = x;
    for (int k = 0; k < K_STEPS; ++k) {
        float* o = (k & 1) ? out : hA;    // k=7 (last, odd) writes d_out
        k_prop<<<prop_grid, 256, 0, stream>>>(in, o, offsets, csr, N_NODES);
        in = o;
    }
}

// Round 11
// 514.423 us; speedup vs baseline: 1.0752x; 1.0752x over previous
//
#include <hip/hip_runtime.h>

#define N_NODES 100000
#define N_EDGES 1600000
#define D_FEAT  64
#define K_STEPS 8

#define CHUNK   4096
#define EPT     16                              // CHUNK / 256
#define BSHIFT  7
#define NBUCK   ((N_NODES + 127) >> 7)          // 782 buckets of 128 dsts
#define NBLK_P  ((N_EDGES + CHUNK - 1) / CHUNK) // 391 partition blocks
#define NSCAN   (NBUCK * NBLK_P)                // 305762
#define NB_BS   ((NSCAN + 255) / 256)           // 1195 scan blocks

typedef unsigned long long u64;
typedef float f4 __attribute__((ext_vector_type(4)));

// Pass 1: per-block bucket histogram via LDS atomics (no global atomics).
__global__ __launch_bounds__(256)
void k_p1_count(const int* __restrict__ dst, int* __restrict__ gcount, int n) {
    __shared__ int lh[NBUCK];
    for (int j = threadIdx.x; j < NBUCK; j += 256) lh[j] = 0;
    __syncthreads();
    int base = blockIdx.x * CHUNK + threadIdx.x;
    #pragma unroll
    for (int k = 0; k < EPT; ++k) {
        int i = base + k * 256;
        if (i < n) atomicAdd(&lh[dst[i] >> BSHIFT], 1);
    }
    __syncthreads();
    for (int j = threadIdx.x; j < NBUCK; j += 256)
        gcount[j * NBLK_P + blockIdx.x] = lh[j];   // bucket-major for the scan
}

// Scan phase 1: per-block sums of 256 entries.
__global__ void k_bsum(const int* __restrict__ a, int* __restrict__ blockSums, int n) {
    __shared__ int ws[4];
    int t = threadIdx.x;
    int i = blockIdx.x * 256 + t;
    int c = (i < n) ? a[i] : 0;
    for (int off = 32; off; off >>= 1) c += __shfl_down(c, off);
    if ((t & 63) == 0) ws[t >> 6] = c;
    __syncthreads();
    if (t == 0) blockSums[blockIdx.x] = ws[0] + ws[1] + ws[2] + ws[3];
}

// Scan phase 2: single 1024-thread block scans nb block sums (chunked).
__global__ void k_sscan2(const int* __restrict__ blockSums, int* __restrict__ blockPrefix,
                         int nb) {
    __shared__ int sh[1024];
    int t = threadIdx.x;
    const int CH = (nb + 1023) / 1024;
    int b0 = t * CH;
    int s = 0;
    for (int k = 0; k < CH; ++k) { int i = b0 + k; if (i < nb) s += blockSums[i]; }
    sh[t] = s;
    __syncthreads();
    for (int off = 1; off < 1024; off <<= 1) {
        int u = (t >= off) ? sh[t - off] : 0;
        __syncthreads();
        sh[t] += u;
        __syncthreads();
    }
    int run = (t == 0) ? 0 : sh[t - 1];
    for (int k = 0; k < CH; ++k) {
        int i = b0 + k;
        if (i < nb) { int c = blockSums[i]; blockPrefix[i] = run; run += c; }
    }
}

// Scan phase 3: in-place exclusive scan of gcount (+ block prefix).
__global__ void k_bscan(int* __restrict__ a, const int* __restrict__ blockPrefix, int n) {
    __shared__ int sh[256];
    int t = threadIdx.x;
    int i = blockIdx.x * 256 + t;
    int c = (i < n) ? a[i] : 0;
    sh[t] = c;
    __syncthreads();
    for (int off = 1; off < 256; off <<= 1) {
        int u = (t >= off) ? sh[t - off] : 0;
        __syncthreads();
        sh[t] += u;
        __syncthreads();
    }
    int excl = sh[t] - c + blockPrefix[blockIdx.x];
    if (i < n) a[i] = excl;
}

// Pass 3: partition edges into bucket order. Rank within (block,bucket) from a
// returning LDS atomic; write position = scanned gcount + rank. No global atomics.
__global__ __launch_bounds__(256)
void k_p3_part(const int* __restrict__ src, const int* __restrict__ dst,
               const float* __restrict__ w, const int* __restrict__ gcount,
               u64* __restrict__ partSW, int* __restrict__ partDst, int n) {
    __shared__ int lc[NBUCK];
    for (int j = threadIdx.x; j < NBUCK; j += 256)
        lc[j] = gcount[j * NBLK_P + blockIdx.x];
    __syncthreads();
    int base = blockIdx.x * CHUNK + threadIdx.x;
    #pragma unroll
    for (int k = 0; k < EPT; ++k) {
        int i = base + k * 256;
        if (i < n) {
            int d = dst[i];
            int pos = atomicAdd(&lc[d >> BSHIFT], 1);
            partSW[pos]  = ((u64)__float_as_uint(w[i]) << 32) | (unsigned)src[i];
            partDst[pos] = d;
        }
    }
}

// Pass 4: one block per bucket (~2046 edges, 128 dsts). LDS count -> LDS scan
// -> offsets + final CSR placement. All within-bucket; csr writes hit an
// L2-hot ~16KB window.
__global__ __launch_bounds__(256)
void k_p4_csr(const u64* __restrict__ partSW, const int* __restrict__ partDst,
              const int* __restrict__ gcount, int* __restrict__ offsets,
              u64* __restrict__ csr, int n) {
    __shared__ int lcnt[128];
    __shared__ int sh[128];
    int b = blockIdx.x;
    int t = threadIdx.x;
    int dstBase = b << BSHIFT;
    int bstart = gcount[b * NBLK_P];
    int bend   = (b == NBUCK - 1) ? N_EDGES : gcount[(b + 1) * NBLK_P];
    if (t < 128) lcnt[t] = 0;
    __syncthreads();
    for (int i = bstart + t; i < bend; i += 256)
        atomicAdd(&lcnt[partDst[i] - dstBase], 1);
    __syncthreads();
    int c = (t < 128) ? lcnt[t] : 0;
    if (t < 128) sh[t] = c;
    __syncthreads();
    for (int off = 1; off < 128; off <<= 1) {
        int u = (t >= off && t < 128) ? sh[t - off] : 0;
        __syncthreads();
        if (t < 128) sh[t] += u;
        __syncthreads();
    }
    if (t < 128) {
        int excl = sh[t] - c;
        int v = dstBase + t;
        if (v < n) offsets[v] = bstart + excl;
        lcnt[t] = excl;                 // becomes within-bucket cursor
    }
    __syncthreads();
    for (int i = bstart + t; i < bend; i += 256) {
        int ld = partDst[i] - dstBase;
        int r = atomicAdd(&lcnt[ld], 1);
        csr[bstart + r] = partSW[i];
    }
    if (b == 0 && t == 0) offsets[n] = N_EDGES;
}

// One wave per node. lane = (edge_slot eg=lane>>3 [8 slots], fl=lane&7).
// 2-way unrolled: 16 edges in flight per iteration. OOB slot predicated to
// (row 0, w=0). All accesses cached: h + csr stay L2/LLC-resident.
__global__ __launch_bounds__(256)
void k_prop(const float* __restrict__ hin, float* __restrict__ hout,
            const int* __restrict__ offsets, const u64* __restrict__ csr, int n) {
    int wave = (blockIdx.x * blockDim.x + threadIdx.x) >> 6;
    int lane = threadIdx.x & 63;
    if (wave >= n) return;
    int b = offsets[wave];
    int e = offsets[wave + 1];
    int eg = lane >> 3;        // edge slot 0..7
    int fl = lane & 7;         // feature group (8 floats)
    f4 a0 = {0.f, 0.f, 0.f, 0.f};
    f4 a1 = {0.f, 0.f, 0.f, 0.f};
    f4 c0 = {0.f, 0.f, 0.f, 0.f};
    f4 c1 = {0.f, 0.f, 0.f, 0.f};
    for (int i = b + eg; i < e; i += 16) {
        int  iB  = i + 8;
        bool okB = iB < e;
        u64 pA = csr[i];
        u64 pB = okB ? csr[iB] : 0;
        int   sA = (int)(pA & 0xffffffffu);
        float wA = __uint_as_float((unsigned)(pA >> 32));
        int   sB = okB ? (int)(pB & 0xffffffffu) : 0;
        float wB = okB ? __uint_as_float((unsigned)(pB >> 32)) : 0.f;
        const f4* rA = reinterpret_cast<const f4*>(&hin[((size_t)sA << 6) + (fl << 3)]);
        const f4* rB = reinterpret_cast<const f4*>(&hin[((size_t)sB << 6) + (fl << 3)]);
        f4 vA0 = rA[0], vA1 = rA[1];
        f4 vB0 = rB[0], vB1 = rB[1];
        a0.x = fmaf(wA, vA0.x, a0.x); a0.y = fmaf(wA, vA0.y, a0.y);
        a0.z = fmaf(wA, vA0.z, a0.z); a0.w = fmaf(wA, vA0.w, a0.w);
        a1.x = fmaf(wA, vA1.x, a1.x); a1.y = fmaf(wA, vA1.y, a1.y);
        a1.z = fmaf(wA, vA1.z, a1.z); a1.w = fmaf(wA, vA1.w, a1.w);
        c0.x = fmaf(wB, vB0.x, c0.x); c0.y = fmaf(wB, vB0.y, c0.y);
        c0.z = fmaf(wB, vB0.z, c0.z); c0.w = fmaf(wB, vB0.w, c0.w);
        c1.x = fmaf(wB, vB1.x, c1.x); c1.y = fmaf(wB, vB1.y, c1.y);
        c1.w = fmaf(wB, vB1.w, c1.w); c1.z = fmaf(wB, vB1.z, c1.z);
    }
    a0.x += c0.x; a0.y += c0.y; a0.z += c0.z; a0.w += c0.w;
    a1.x += c1.x; a1.y += c1.y; a1.z += c1.z; a1.w += c1.w;
    #pragma unroll
    for (int off = 8; off < 64; off <<= 1) {
        a0.x += __shfl_xor(a0.x, off);
        a0.y += __shfl_xor(a0.y, off);
        a0.z += __shfl_xor(a0.z, off);
        a0.w += __shfl_xor(a0.w, off);
        a1.x += __shfl_xor(a1.x, off);
        a1.y += __shfl_xor(a1.y, off);
        a1.z += __shfl_xor(a1.z, off);
        a1.w += __shfl_xor(a1.w, off);
    }
    if (eg == 0) {
        f4* o = reinterpret_cast<f4*>(&hout[((size_t)wave << 6) + (fl << 3)]);
        o[0] = a0;
        o[1] = a1;
    }
}

extern "C" void kernel_launch(void* const* d_in, const int* in_sizes, int n_in,
                              void* d_out, int out_size, void* d_ws, size_t ws_size,
                              hipStream_t stream) {
    const float* x   = (const float*)d_in[0];
    const float* ew  = (const float*)d_in[1];
    const int*   src = (const int*)d_in[2];
    const int*   dst = (const int*)d_in[3];
    float* out = (float*)d_out;

    // Workspace (~38.9 MB). partSW/partDst/gcount alias hA (19.2+1.22 MB
    // inside hA's 25.6 MB): all dead before the first k_prop writes hA.
    // Prop chain ping-pongs hA <-> d_out; k=7 (odd) lands in d_out.
    float* hA        = (float*)d_ws;                            // N*D floats (25.6MB)
    u64*   partSW    = (u64*)d_ws;                              // E x 8B (aliases hA)
    int*   partDst   = (int*)(partSW + N_EDGES);                // E ints
    int*   gcount    = partDst + N_EDGES;                       // NSCAN ints (1.22MB)
    u64*   csr       = (u64*)(hA + (size_t)N_NODES * D_FEAT);   // E x 8B packed (w,src)
    int*   offsets   = (int*)(csr + N_EDGES);                   // N+1 ints
    int*   blockSums = offsets + (N_NODES + 1);                 // NB_BS ints
    int*   blockPref = blockSums + NB_BS;                       // NB_BS ints

    k_p1_count<<<NBLK_P, 256, 0, stream>>>(dst, gcount, N_EDGES);
    k_bsum    <<<NB_BS, 256, 0, stream>>>(gcount, blockSums, NSCAN);
    k_sscan2  <<<1, 1024, 0, stream>>>(blockSums, blockPref, NB_BS);
    k_bscan   <<<NB_BS, 256, 0, stream>>>(gcount, blockPref, NSCAN);
    k_p3_part <<<NBLK_P, 256, 0, stream>>>(src, dst, ew, gcount, partSW, partDst, N_EDGES);
    k_p4_csr  <<<NBUCK, 256, 0, stream>>>(partSW, partDst, gcount, offsets, csr, N_NODES);

    const int prop_grid = (N_NODES * 64 + 255) / 256;
    const float* in = x;
    for (int k = 0; k < K_STEPS; ++k) {
        float* o = (k & 1) ? out : hA;    // k=7 (last, odd) writes d_out
        k_prop<<<prop_grid, 256, 0, stream>>>(in, o, offsets, csr, N_NODES);
        in = o;
    }
}

// Round 12
// 502.745 us; speedup vs baseline: 1.1002x; 1.0232x over previous
//
#include <hip/hip_runtime.h>

#define N_NODES 100000
#define N_EDGES 1600000
#define D_FEAT  64
#define K_STEPS 8

#define CHUNK   2048
#define EPT     8                               // CHUNK / 256
#define BSHIFT  7
#define NBUCK   ((N_NODES + 127) >> 7)          // 782 buckets of 128 dsts
#define NBLK_P  ((N_EDGES + CHUNK - 1) / CHUNK) // 782 partition blocks
#define NSCAN   (NBUCK * NBLK_P)                // 611,524
#define NB_BS   ((NSCAN + 255) / 256)           // 2389 scan blocks

typedef unsigned long long u64;
typedef float f4 __attribute__((ext_vector_type(4)));

// Pass 1: per-block bucket histogram via LDS atomics (no global atomics).
__global__ __launch_bounds__(256)
void k_p1_count(const int* __restrict__ dst, int* __restrict__ gcount, int n) {
    __shared__ int lh[NBUCK];
    for (int j = threadIdx.x; j < NBUCK; j += 256) lh[j] = 0;
    __syncthreads();
    int base = blockIdx.x * CHUNK + threadIdx.x;
    #pragma unroll
    for (int k = 0; k < EPT; ++k) {
        int i = base + k * 256;
        if (i < n) atomicAdd(&lh[dst[i] >> BSHIFT], 1);
    }
    __syncthreads();
    for (int j = threadIdx.x; j < NBUCK; j += 256)
        gcount[j * NBLK_P + blockIdx.x] = lh[j];   // bucket-major for the scan
}

// Scan phase 1: per-block sums of 256 entries.
__global__ void k_bsum(const int* __restrict__ a, int* __restrict__ blockSums, int n) {
    __shared__ int ws[4];
    int t = threadIdx.x;
    int i = blockIdx.x * 256 + t;
    int c = (i < n) ? a[i] : 0;
    for (int off = 32; off; off >>= 1) c += __shfl_down(c, off);
    if ((t & 63) == 0) ws[t >> 6] = c;
    __syncthreads();
    if (t == 0) blockSums[blockIdx.x] = ws[0] + ws[1] + ws[2] + ws[3];
}

// Scan phase 2: single 1024-thread block scans nb block sums (chunked).
__global__ void k_sscan2(const int* __restrict__ blockSums, int* __restrict__ blockPrefix,
                         int nb) {
    __shared__ int sh[1024];
    int t = threadIdx.x;
    const int CH = (nb + 1023) / 1024;
    int b0 = t * CH;
    int s = 0;
    for (int k = 0; k < CH; ++k) { int i = b0 + k; if (i < nb) s += blockSums[i]; }
    sh[t] = s;
    __syncthreads();
    for (int off = 1; off < 1024; off <<= 1) {
        int u = (t >= off) ? sh[t - off] : 0;
        __syncthreads();
        sh[t] += u;
        __syncthreads();
    }
    int run = (t == 0) ? 0 : sh[t - 1];
    for (int k = 0; k < CH; ++k) {
        int i = b0 + k;
        if (i < nb) { int c = blockSums[i]; blockPrefix[i] = run; run += c; }
    }
}

// Scan phase 3: in-place exclusive scan of gcount (+ block prefix).
__global__ void k_bscan(int* __restrict__ a, const int* __restrict__ blockPrefix, int n) {
    __shared__ int sh[256];
    int t = threadIdx.x;
    int i = blockIdx.x * 256 + t;
    int c = (i < n) ? a[i] : 0;
    sh[t] = c;
    __syncthreads();
    for (int off = 1; off < 256; off <<= 1) {
        int u = (t >= off) ? sh[t - off] : 0;
        __syncthreads();
        sh[t] += u;
        __syncthreads();
    }
    int excl = sh[t] - c + blockPrefix[blockIdx.x];
    if (i < n) a[i] = excl;
}

// Pass 3: partition edges into bucket order. Payload packs [w:32][ld:7][src:17]
// (ld = dst low 7 bits; bucket id is implicit in position) -> ONE 8B store per
// edge, no partDst array. Rank from returning LDS atomic; no global atomics.
__global__ __launch_bounds__(256)
void k_p3_part(const int* __restrict__ src, const int* __restrict__ dst,
               const float* __restrict__ w, const int* __restrict__ gcount,
               u64* __restrict__ partSW, int n) {
    __shared__ int lc[NBUCK];
    for (int j = threadIdx.x; j < NBUCK; j += 256)
        lc[j] = gcount[j * NBLK_P + blockIdx.x];
    __syncthreads();
    int base = blockIdx.x * CHUNK + threadIdx.x;
    #pragma unroll
    for (int k = 0; k < EPT; ++k) {
        int i = base + k * 256;
        if (i < n) {
            int d = dst[i];
            int pos = atomicAdd(&lc[d >> BSHIFT], 1);
            u64 p = ((u64)__float_as_uint(w[i]) << 32)
                  | ((u64)(d & 127) << 17)
                  | (unsigned)src[i];
            partSW[pos] = p;
        }
    }
}

// Pass 4: one block per bucket (~2046 edges, 128 dsts). LDS count -> LDS scan
// -> offsets + final CSR placement (entry rewritten as [w:32][src:32] so the
// prop kernel is unchanged). All within-bucket; csr writes hit a ~16KB window.
__global__ __launch_bounds__(256)
void k_p4_csr(const u64* __restrict__ partSW, const int* __restrict__ gcount,
              int* __restrict__ offsets, u64* __restrict__ csr, int n) {
    __shared__ int lcnt[128];
    __shared__ int sh[128];
    int b = blockIdx.x;
    int t = threadIdx.x;
    int dstBase = b << BSHIFT;
    int bstart = gcount[b * NBLK_P];
    int bend   = (b == NBUCK - 1) ? N_EDGES : gcount[(b + 1) * NBLK_P];
    if (t < 128) lcnt[t] = 0;
    __syncthreads();
    for (int i = bstart + t; i < bend; i += 256)
        atomicAdd(&lcnt[(int)((partSW[i] >> 17) & 127u)], 1);
    __syncthreads();
    int c = (t < 128) ? lcnt[t] : 0;
    if (t < 128) sh[t] = c;
    __syncthreads();
    for (int off = 1; off < 128; off <<= 1) {
        int u = (t >= off && t < 128) ? sh[t - off] : 0;
        __syncthreads();
        if (t < 128) sh[t] += u;
        __syncthreads();
    }
    if (t < 128) {
        int excl = sh[t] - c;
        int v = dstBase + t;
        if (v < n) offsets[v] = bstart + excl;
        lcnt[t] = excl;                 // becomes within-bucket cursor
    }
    __syncthreads();
    for (int i = bstart + t; i < bend; i += 256) {
        u64 p = partSW[i];
        int ld = (int)((p >> 17) & 127u);
        int r = atomicAdd(&lcnt[ld], 1);
        csr[bstart + r] = (p & 0xFFFFFFFF00000000ull) | (p & 0x1FFFFull);
    }
    if (b == 0 && t == 0) offsets[n] = N_EDGES;
}

// One wave per node. lane = (edge_slot eg=lane>>3 [8 slots], fl=lane&7).
// 2-way unrolled: 16 edges in flight per iteration. OOB slot predicated to
// (row 0, w=0). All accesses cached: h + csr stay L2/LLC-resident.
__global__ __launch_bounds__(256)
void k_prop(const float* __restrict__ hin, float* __restrict__ hout,
            const int* __restrict__ offsets, const u64* __restrict__ csr, int n) {
    int wave = (blockIdx.x * blockDim.x + threadIdx.x) >> 6;
    int lane = threadIdx.x & 63;
    if (wave >= n) return;
    int b = offsets[wave];
    int e = offsets[wave + 1];
    int eg = lane >> 3;        // edge slot 0..7
    int fl = lane & 7;         // feature group (8 floats)
    f4 a0 = {0.f, 0.f, 0.f, 0.f};
    f4 a1 = {0.f, 0.f, 0.f, 0.f};
    f4 c0 = {0.f, 0.f, 0.f, 0.f};
    f4 c1 = {0.f, 0.f, 0.f, 0.f};
    for (int i = b + eg; i < e; i += 16) {
        int  iB  = i + 8;
        bool okB = iB < e;
        u64 pA = csr[i];
        u64 pB = okB ? csr[iB] : 0;
        int   sA = (int)(pA & 0xffffffffu);
        float wA = __uint_as_float((unsigned)(pA >> 32));
        int   sB = okB ? (int)(pB & 0xffffffffu) : 0;
        float wB = okB ? __uint_as_float((unsigned)(pB >> 32)) : 0.f;
        const f4* rA = reinterpret_cast<const f4*>(&hin[((size_t)sA << 6) + (fl << 3)]);
        const f4* rB = reinterpret_cast<const f4*>(&hin[((size_t)sB << 6) + (fl << 3)]);
        f4 vA0 = rA[0], vA1 = rA[1];
        f4 vB0 = rB[0], vB1 = rB[1];
        a0.x = fmaf(wA, vA0.x, a0.x); a0.y = fmaf(wA, vA0.y, a0.y);
        a0.z = fmaf(wA, vA0.z, a0.z); a0.w = fmaf(wA, vA0.w, a0.w);
        a1.x = fmaf(wA, vA1.x, a1.x); a1.y = fmaf(wA, vA1.y, a1.y);
        a1.z = fmaf(wA, vA1.z, a1.z); a1.w = fmaf(wA, vA1.w, a1.w);
        c0.x = fmaf(wB, vB0.x, c0.x); c0.y = fmaf(wB, vB0.y, c0.y);
        c0.z = fmaf(wB, vB0.z, c0.z); c0.w = fmaf(wB, vB0.w, c0.w);
        c1.x = fmaf(wB, vB1.x, c1.x); c1.y = fmaf(wB, vB1.y, c1.y);
        c1.z = fmaf(wB, vB1.z, c1.z); c1.w = fmaf(wB, vB1.w, c1.w);
    }
    a0.x += c0.x; a0.y += c0.y; a0.z += c0.z; a0.w += c0.w;
    a1.x += c1.x; a1.y += c1.y; a1.z += c1.z; a1.w += c1.w;
    #pragma unroll
    for (int off = 8; off < 64; off <<= 1) {
        a0.x += __shfl_xor(a0.x, off);
        a0.y += __shfl_xor(a0.y, off);
        a0.z += __shfl_xor(a0.z, off);
        a0.w += __shfl_xor(a0.w, off);
        a1.x += __shfl_xor(a1.x, off);
        a1.y += __shfl_xor(a1.y, off);
        a1.z += __shfl_xor(a1.z, off);
        a1.w += __shfl_xor(a1.w, off);
    }
    if (eg == 0) {
        f4* o = reinterpret_cast<f4*>(&hout[((size_t)wave << 6) + (fl << 3)]);
        o[0] = a0;
        o[1] = a1;
    }
}

extern "C" void kernel_launch(void* const* d_in, const int* in_sizes, int n_in,
                              void* d_out, int out_size, void* d_ws, size_t ws_size,
                              hipStream_t stream) {
    const float* x   = (const float*)d_in[0];
    const float* ew  = (const float*)d_in[1];
    const int*   src = (const int*)d_in[2];
    const int*   dst = (const int*)d_in[3];
    float* out = (float*)d_out;

    // Workspace (~38.5 MB). partSW (12.8MB) + gcount (2.4MB) alias hA
    // (25.6MB): both dead before the first k_prop writes hA. Prop chain
    // ping-pongs hA <-> d_out; k=7 (odd) lands in d_out.
    float* hA        = (float*)d_ws;                            // N*D floats (25.6MB)
    u64*   partSW    = (u64*)d_ws;                              // E x 8B (aliases hA)
    int*   gcount    = (int*)(partSW + N_EDGES);                // NSCAN ints (2.4MB)
    u64*   csr       = (u64*)(hA + (size_t)N_NODES * D_FEAT);   // E x 8B packed (w,src)
    int*   offsets   = (int*)(csr + N_EDGES);                   // N+1 ints
    int*   blockSums = offsets + (N_NODES + 1);                 // NB_BS ints
    int*   blockPref = blockSums + NB_BS;                       // NB_BS ints

    k_p1_count<<<NBLK_P, 256, 0, stream>>>(dst, gcount, N_EDGES);
    k_bsum    <<<NB_BS, 256, 0, stream>>>(gcount, blockSums, NSCAN);
    k_sscan2  <<<1, 1024, 0, stream>>>(blockSums, blockPref, NB_BS);
    k_bscan   <<<NB_BS, 256, 0, stream>>>(gcount, blockPref, NSCAN);
    k_p3_part <<<NBLK_P, 256, 0, stream>>>(src, dst, ew, gcount, partSW, N_EDGES);
    k_p4_csr  <<<NBUCK, 256, 0, stream>>>(partSW, gcount, offsets, csr, N_NODES);

    const int prop_grid = (N_NODES * 64 + 255) / 256;
    const float* in = x;
    for (int k = 0; k < K_STEPS; ++k) {
        float* o = (k & 1) ? out : hA;    // k=7 (last, odd) writes d_out
        k_prop<<<prop_grid, 256, 0, stream>>>(in, o, offsets, csr, N_NODES);
        in = o;
    }
}